// Round 3
// baseline (2370.480 us; speedup 1.0000x reference)
//
#include <hip/hip_runtime.h>
#include <hip/hip_bf16.h>
#include <math.h>

#define N_NODES 512
#define N_EDGES 4096
#define D_NODE 256
#define D3 768
#define H_GNN 512
#define N_OBJ_CLS 160
#define N_REL_CLS 26

// ---------------- Fused PointNet: (B,CIN,P) -> (B,256) ----------------
// per-point MLP CIN->64->128->256 (relu,relu,none) then max over P.
// One block per sample b. 4 waves; wave wv owns points [16*wv,16*wv+16) of
// each 64-point tile. Cross-wave max reduction at the end via pm[][] LDS.
template<int CIN, int P>
__global__ __launch_bounds__(256) void pointnet_kernel(
    const float* __restrict__ in,
    const float* __restrict__ w1, const float* __restrict__ b1,
    const float* __restrict__ w2, const float* __restrict__ b2,
    const float* __restrict__ w3, const float* __restrict__ b3,
    float* __restrict__ out)
{
  __shared__ float h1[64][68];    // 64 points x 64 ch
  __shared__ float h2[64][132];   // 64 points x 128 ch
  __shared__ float pm[4][256];    // per-wave partial max over its points
  const int tid = threadIdx.x;
  const int wv = tid >> 6;        // wave id 0..3
  const int ln = tid & 63;        // lane
  const int b = blockIdx.x;
  const float* inb = in + (size_t)b * CIN * P;

  float w1c[CIN];
#pragma unroll
  for (int c = 0; c < CIN; ++c) w1c[c] = w1[c * 64 + ln];
  const float b1v = b1[ln];
  const float b2v0 = b2[ln], b2v1 = b2[ln + 64];

  float mx[4];
#pragma unroll
  for (int j = 0; j < 4; ++j) mx[j] = -INFINITY;

  for (int t0 = 0; t0 < P; t0 += 64) {
    // ---- layer 1: h1[p][ln] ----
#pragma unroll
    for (int k = 0; k < 16; ++k) {
      const int p = wv * 16 + k;
      float acc = b1v;
#pragma unroll
      for (int c = 0; c < CIN; ++c) acc += inb[c * P + t0 + p] * w1c[c];
      h1[p][ln] = fmaxf(acc, 0.0f);
    }
    __syncthreads();   // h1 writes visible to all waves
    // ---- layer 2: h2[p][ln], h2[p][ln+64] ----
    {
      float accB0[16], accB1[16];
#pragma unroll
      for (int pp = 0; pp < 16; ++pp) { accB0[pp] = b2v0; accB1[pp] = b2v1; }
      for (int c0 = 0; c0 < 64; c0 += 4) {
        float wa[4], wb[4];
#pragma unroll
        for (int i = 0; i < 4; ++i) {
          wa[i] = w2[(c0 + i) * 128 + ln];
          wb[i] = w2[(c0 + i) * 128 + ln + 64];
        }
#pragma unroll
        for (int pp = 0; pp < 16; ++pp) {
          const float4 h = *reinterpret_cast<const float4*>(&h1[wv * 16 + pp][c0]);
          accB0[pp] += h.x * wa[0] + h.y * wa[1] + h.z * wa[2] + h.w * wa[3];
          accB1[pp] += h.x * wb[0] + h.y * wb[1] + h.z * wb[2] + h.w * wb[3];
        }
      }
#pragma unroll
      for (int pp = 0; pp < 16; ++pp) {
        h2[wv * 16 + pp][ln]      = fmaxf(accB0[pp], 0.0f);
        h2[wv * 16 + pp][ln + 64] = fmaxf(accB1[pp], 0.0f);
      }
    }
    __syncthreads();   // h2 writes visible to all waves
    // ---- layer 3 + running max over this wave's points ----
    {
      float accC[16][4];
#pragma unroll
      for (int pp = 0; pp < 16; ++pp)
#pragma unroll
        for (int j = 0; j < 4; ++j) accC[pp][j] = 0.0f;
      for (int c0 = 0; c0 < 128; c0 += 4) {
        float w3v[4][4];
#pragma unroll
        for (int i = 0; i < 4; ++i)
#pragma unroll
          for (int j = 0; j < 4; ++j)
            w3v[i][j] = w3[(c0 + i) * 256 + ln + 64 * j];
#pragma unroll
        for (int pp = 0; pp < 16; ++pp) {
          const float4 h = *reinterpret_cast<const float4*>(&h2[wv * 16 + pp][c0]);
#pragma unroll
          for (int j = 0; j < 4; ++j)
            accC[pp][j] += h.x * w3v[0][j] + h.y * w3v[1][j] + h.z * w3v[2][j] + h.w * w3v[3][j];
        }
      }
#pragma unroll
      for (int pp = 0; pp < 16; ++pp)
#pragma unroll
        for (int j = 0; j < 4; ++j) mx[j] = fmaxf(mx[j], accC[pp][j]);
    }
  }
  // ---- cross-wave max reduction (the round-2 bug fix) ----
#pragma unroll
  for (int j = 0; j < 4; ++j) pm[wv][ln + 64 * j] = mx[j];
  __syncthreads();
  {
    const int ch = tid;  // 256 channels, one per thread
    const float m = fmaxf(fmaxf(pm[0][ch], pm[1][ch]), fmaxf(pm[2][ch], pm[3][ch]));
    out[(size_t)b * 256 + ch] = m + b3[ch];
  }
}

// ---------------- Generic tiled GEMM: C = act(A(MxK,lda) @ W(KxN) + bias) ----
// ACT: 0 none, 1 relu, 2 sigmoid. K must be a multiple of 16 (true here).
template<int ACT>
__global__ __launch_bounds__(256) void gemm_kernel(
    const float* __restrict__ A, int lda,
    const float* __restrict__ W,
    const float* __restrict__ bias,
    float* __restrict__ C, int ldc,
    int M, int N, int K)
{
  __shared__ float As[16][68];   // [k][m]
  __shared__ float Ws[16][68];   // [k][n]
  const int tid = threadIdx.x;
  const int tx = tid & 15, ty = tid >> 4;
  const int bm = blockIdx.y * 64, bn = blockIdx.x * 64;
  float acc[4][4] = {};
  const int ar = tid >> 2, ac = (tid & 3) * 4;   // A tile load: row, col4
  const int wr = tid >> 4, wc = (tid & 15) * 4;  // W tile load

  for (int k0 = 0; k0 < K; k0 += 16) {
    float4 av = make_float4(0.f, 0.f, 0.f, 0.f);
    if (bm + ar < M)
      av = *reinterpret_cast<const float4*>(&A[(size_t)(bm + ar) * lda + k0 + ac]);
    As[ac + 0][ar] = av.x; As[ac + 1][ar] = av.y;
    As[ac + 2][ar] = av.z; As[ac + 3][ar] = av.w;
#pragma unroll
    for (int i = 0; i < 4; ++i) {
      const int col = bn + wc + i;
      Ws[wr][wc + i] = (col < N) ? W[(size_t)(k0 + wr) * N + col] : 0.0f;
    }
    __syncthreads();
#pragma unroll
    for (int k = 0; k < 16; ++k) {
      const float4 a = *reinterpret_cast<const float4*>(&As[k][ty * 4]);
      const float4 bq = *reinterpret_cast<const float4*>(&Ws[k][tx * 4]);
      const float avv[4] = {a.x, a.y, a.z, a.w};
      const float bvv[4] = {bq.x, bq.y, bq.z, bq.w};
#pragma unroll
      for (int i = 0; i < 4; ++i)
#pragma unroll
        for (int j = 0; j < 4; ++j) acc[i][j] += avv[i] * bvv[j];
    }
    __syncthreads();
  }
#pragma unroll
  for (int i = 0; i < 4; ++i) {
    const int row = bm + ty * 4 + i;
    if (row >= M) continue;
#pragma unroll
    for (int j = 0; j < 4; ++j) {
      const int col = bn + tx * 4 + j;
      if (col >= N) continue;
      float v = acc[i][j] + bias[col];
      if (ACT == 1) v = fmaxf(v, 0.0f);
      else if (ACT == 2) v = 1.0f / (1.0f + expf(-v));
      C[(size_t)row * ldc + col] = v;
    }
  }
}

// ---------------- small helper kernels ----------------
__global__ __launch_bounds__(256) void gather_kernel(
    const float* __restrict__ x, const float* __restrict__ e, int estride,
    const int* __restrict__ ei, float* __restrict__ t)
{
  const int i = blockIdx.x;
  const int tid = threadIdx.x;
  const int s = ei[i], o = ei[N_EDGES + i];
  float* tr = t + (size_t)i * D3;
  tr[tid]       = x[(size_t)s * D_NODE + tid];
  tr[256 + tid] = e[(size_t)i * estride + tid];
  tr[512 + tid] = x[(size_t)o * D_NODE + tid];
}

__global__ __launch_bounds__(256) void scatter_kernel(
    const float* __restrict__ h, const int* __restrict__ ei, float* __restrict__ pooled)
{
  const int i = blockIdx.x;
  const int tid = threadIdx.x;
  const int s = ei[i], o = ei[N_EDGES + i];
  atomicAdd(&pooled[(size_t)s * D_NODE + tid], h[(size_t)i * D3 + tid]);
  atomicAdd(&pooled[(size_t)o * D_NODE + tid], h[(size_t)i * D3 + 512 + tid]);
}

__global__ __launch_bounds__(256) void count_kernel(const int* __restrict__ ei,
                                                    float* __restrict__ cnt)
{
  const int i = blockIdx.x * blockDim.x + threadIdx.x;
  if (i < 2 * N_EDGES) atomicAdd(&cnt[ei[i]], 1.0f);
}

__global__ __launch_bounds__(256) void avg_kernel(const float* __restrict__ pooled,
                                                  const float* __restrict__ cnt,
                                                  float* __restrict__ avg)
{
  const int i = blockIdx.x * 256 + threadIdx.x;
  avg[i] = pooled[i] / fmaxf(cnt[i >> 8], 1.0f);
}

__global__ __launch_bounds__(256) void logsoftmax_kernel(const float* __restrict__ logits,
                                                         float* __restrict__ out)
{
  __shared__ float red[256];
  const int r = blockIdx.x, tid = threadIdx.x;
  const float v = (tid < N_OBJ_CLS) ? logits[(size_t)r * N_OBJ_CLS + tid] : -INFINITY;
  red[tid] = v;
  __syncthreads();
  for (int s = 128; s > 0; s >>= 1) {
    if (tid < s) red[tid] = fmaxf(red[tid], red[tid + s]);
    __syncthreads();
  }
  const float mxv = red[0];
  __syncthreads();
  red[tid] = (tid < N_OBJ_CLS) ? expf(v - mxv) : 0.0f;
  __syncthreads();
  for (int s = 128; s > 0; s >>= 1) {
    if (tid < s) red[tid] += red[tid + s];
    __syncthreads();
  }
  const float lse = mxv + logf(red[0]);
  if (tid < N_OBJ_CLS) out[(size_t)r * N_OBJ_CLS + tid] = v - lse;
}

// ---------------- launch ----------------
extern "C" void kernel_launch(void* const* d_in, const int* in_sizes, int n_in,
                              void* d_out, int out_size, void* d_ws, size_t ws_size,
                              hipStream_t stream)
{
  const float* obj_points = (const float*)d_in[0];
  const float* rel_points = (const float*)d_in[1];
  const int*   edge_index = (const int*)d_in[2];
  const float* obj_w1 = (const float*)d_in[3];
  const float* obj_b1 = (const float*)d_in[4];
  const float* obj_w2 = (const float*)d_in[5];
  const float* obj_b2 = (const float*)d_in[6];
  const float* obj_w3 = (const float*)d_in[7];
  const float* obj_b3 = (const float*)d_in[8];
  const float* rel_w1 = (const float*)d_in[9];
  const float* rel_b1 = (const float*)d_in[10];
  const float* rel_w2 = (const float*)d_in[11];
  const float* rel_b2 = (const float*)d_in[12];
  const float* rel_w3 = (const float*)d_in[13];
  const float* rel_b3 = (const float*)d_in[14];
  const float* g_tw1 = (const float*)d_in[15];
  const float* g_tb1 = (const float*)d_in[16];
  const float* g_tw2 = (const float*)d_in[17];
  const float* g_tb2 = (const float*)d_in[18];
  const float* g_nw1 = (const float*)d_in[19];
  const float* g_nb1 = (const float*)d_in[20];
  const float* g_nw2 = (const float*)d_in[21];
  const float* g_nb2 = (const float*)d_in[22];
  const float* oc_w1 = (const float*)d_in[23];
  const float* oc_b1 = (const float*)d_in[24];
  const float* oc_w2 = (const float*)d_in[25];
  const float* oc_b2 = (const float*)d_in[26];
  const float* oc_w3 = (const float*)d_in[27];
  const float* oc_b3 = (const float*)d_in[28];
  const float* rc_w1 = (const float*)d_in[29];
  const float* rc_b1 = (const float*)d_in[30];
  const float* rc_w2 = (const float*)d_in[31];
  const float* rc_b2 = (const float*)d_in[32];
  const float* rc_w3 = (const float*)d_in[33];
  const float* rc_b3 = (const float*)d_in[34];
  float* out = (float*)d_out;

  float* ws = (float*)d_ws;
  size_t off = 0;
  float* x0     = ws + off; off += (size_t)N_NODES * D_NODE;
  float* x1     = ws + off; off += (size_t)N_NODES * D_NODE;
  float* e0     = ws + off; off += (size_t)N_EDGES * D_NODE;
  float* tbuf   = ws + off; off += (size_t)N_EDGES * D3;
  float* h1g    = ws + off; off += (size_t)N_EDGES * H_GNN;
  float* h2g    = ws + off; off += (size_t)N_EDGES * D3;
  float* pooled = ws + off; off += (size_t)N_NODES * D_NODE;
  float* cntf   = ws + off; off += 512;
  float* avgb   = ws + off; off += (size_t)N_NODES * D_NODE;
  float* nh     = ws + off; off += (size_t)N_NODES * H_GNN;
  // heads alias onto buffers that are dead after the GNN
  float* hh1    = tbuf;   // up to 4096x512
  float* hh2    = h1g;    // up to 4096x256
  float* logits = pooled; // 512x160

  // PointNets
  pointnet_kernel<3, 512><<<N_NODES, 256, 0, stream>>>(
      obj_points, obj_w1, obj_b1, obj_w2, obj_b2, obj_w3, obj_b3, x0);
  pointnet_kernel<4, 256><<<N_EDGES, 256, 0, stream>>>(
      rel_points, rel_w1, rel_b1, rel_w2, rel_b2, rel_w3, rel_b3, e0);

  // degree counts (same for both layers)
  hipMemsetAsync(cntf, 0, 512 * sizeof(float), stream);
  count_kernel<<<32, 256, 0, stream>>>(edge_index, cntf);

  float* xcur = x0;
  float* xnext = x1;
  const float* e_ptr = e0; int estride = D_NODE;
  for (int l = 0; l < 2; ++l) {
    gather_kernel<<<N_EDGES, 256, 0, stream>>>(xcur, e_ptr, estride, edge_index, tbuf);
    gemm_kernel<1><<<dim3(H_GNN / 64, N_EDGES / 64), 256, 0, stream>>>(
        tbuf, D3, g_tw1 + (size_t)l * D3 * H_GNN, g_tb1 + l * H_GNN,
        h1g, H_GNN, N_EDGES, H_GNN, D3);
    gemm_kernel<0><<<dim3(D3 / 64, N_EDGES / 64), 256, 0, stream>>>(
        h1g, H_GNN, g_tw2 + (size_t)l * H_GNN * D3, g_tb2 + l * D3,
        h2g, D3, N_EDGES, D3, H_GNN);
    hipMemsetAsync(pooled, 0, (size_t)N_NODES * D_NODE * sizeof(float), stream);
    scatter_kernel<<<N_EDGES, 256, 0, stream>>>(h2g, edge_index, pooled);
    avg_kernel<<<N_NODES, 256, 0, stream>>>(pooled, cntf, avgb);
    gemm_kernel<1><<<dim3(H_GNN / 64, N_NODES / 64), 256, 0, stream>>>(
        avgb, D_NODE, g_nw1 + (size_t)l * D_NODE * H_GNN, g_nb1 + l * H_GNN,
        nh, H_GNN, N_NODES, H_GNN, D_NODE);
    gemm_kernel<0><<<dim3(D_NODE / 64, N_NODES / 64), 256, 0, stream>>>(
        nh, H_GNN, g_nw2 + (size_t)l * H_GNN * D_NODE, g_nb2 + l * D_NODE,
        xnext, D_NODE, N_NODES, D_NODE, H_GNN);
    e_ptr = h2g + D_NODE; estride = D3;
    float* tmp = xcur; xcur = xnext; xnext = tmp;
  }

  // obj head: 256->512->256->160, log_softmax
  gemm_kernel<1><<<dim3(512 / 64, N_NODES / 64), 256, 0, stream>>>(
      xcur, D_NODE, oc_w1, oc_b1, hh1, 512, N_NODES, 512, 256);
  gemm_kernel<1><<<dim3(256 / 64, N_NODES / 64), 256, 0, stream>>>(
      hh1, 512, oc_w2, oc_b2, hh2, 256, N_NODES, 256, 512);
  gemm_kernel<0><<<dim3((N_OBJ_CLS + 63) / 64, N_NODES / 64), 256, 0, stream>>>(
      hh2, 256, oc_w3, oc_b3, logits, N_OBJ_CLS, N_NODES, N_OBJ_CLS, 256);
  logsoftmax_kernel<<<N_NODES, 256, 0, stream>>>(logits, out);

  // rel head: 256->512->256->26, sigmoid (e read in-place from h2g)
  gemm_kernel<1><<<dim3(512 / 64, N_EDGES / 64), 256, 0, stream>>>(
      h2g + D_NODE, D3, rc_w1, rc_b1, hh1, 512, N_EDGES, 512, 256);
  gemm_kernel<1><<<dim3(256 / 64, N_EDGES / 64), 256, 0, stream>>>(
      hh1, 512, rc_w2, rc_b2, hh2, 256, N_EDGES, 256, 512);
  gemm_kernel<2><<<dim3((N_REL_CLS + 63) / 64, N_EDGES / 64), 256, 0, stream>>>(
      hh2, 256, rc_w3, rc_b3, out + (size_t)N_NODES * N_OBJ_CLS, N_REL_CLS,
      N_EDGES, N_REL_CLS, 256);
}

// Round 4
// 885.333 us; speedup vs baseline: 2.6775x; 2.6775x over previous
//
#include <hip/hip_runtime.h>
#include <hip/hip_bf16.h>
#include <math.h>

#define N_NODES 512
#define N_EDGES 4096
#define D_NODE 256
#define D3 768
#define H_GNN 512
#define N_OBJ_CLS 160
#define N_REL_CLS 26

typedef __attribute__((ext_vector_type(8))) short bf16x8;   // 8 bf16 in 4 VGPRs
typedef __attribute__((ext_vector_type(4))) float f32x4;    // MFMA accumulator

__device__ __forceinline__ unsigned short f2bf(float x) {   // RNE f32 -> bf16 bits
  unsigned u = __float_as_uint(x);
  u = u + 0x7FFFu + ((u >> 16) & 1u);
  return (unsigned short)(u >> 16);
}
__device__ __forceinline__ float bf2f(unsigned short h) {
  return __uint_as_float(((unsigned)h) << 16);
}

// wt[n*K + k] = bf16(w[k*N + n])  (transpose + cast; tiny, runs once per launch)
__global__ __launch_bounds__(256) void wtrans_kernel(const float* __restrict__ w,
                                                     unsigned short* __restrict__ wt,
                                                     int K, int N) {
  int i = blockIdx.x * 256 + threadIdx.x;
  if (i >= K * N) return;
  int n = i / K, k = i - n * K;
  wt[i] = f2bf(w[k * N + n]);
}

// ---------------- MFMA PointNet: (B,CIN,P) -> (B,256) ----------------
// L1 (CIN->64) f32 VALU; L2 (64->128) and L3 (128->256) via
// mfma_f32_16x16x32_bf16 with 2-term activation split (Ah*W + Al*W, f32 acc).
// 1 block = 1 sample, 4 waves. Wave N-slices: L2 ch[32w,32w+32), L3 ch[64w,64w+64).
// Frag layouts: A: m=l&15, k=8*(l>>4)+j ; B: n=l&15, same k ; D: col=l&15, row=4*(l>>4)+j.
template<int CIN, int P>
__global__ __launch_bounds__(256) void pointnet_mfma(
    const float* __restrict__ in,
    const float* __restrict__ w1, const float* __restrict__ b1,
    const unsigned short* __restrict__ w2t, const float* __restrict__ b2,
    const unsigned short* __restrict__ w3t, const float* __restrict__ b3,
    float* __restrict__ out)
{
  __shared__ unsigned short h1h[64][72], h1l[64][72];     // 64 pts x 64ch, pad->2-way only
  __shared__ unsigned short h2h[64][136], h2l[64][136];   // 64 pts x 128ch
  const int tid = threadIdx.x;
  const int wv = tid >> 6;
  const int l  = tid & 63;
  const int lr = l & 15;     // frag row/col selector
  const int lg = l >> 4;     // frag k-group
  const int b = blockIdx.x;
  const float* inb = in + (size_t)b * CIN * P;

  float w1c[CIN];
#pragma unroll
  for (int c = 0; c < CIN; ++c) w1c[c] = w1[c * 64 + l];
  const float b1v = b1[l];

  // resident weight B-fragments (shared across all point-tiles & samples)
  bf16x8 w2f[2][2];
#pragma unroll
  for (int nt = 0; nt < 2; ++nt)
#pragma unroll
    for (int kt = 0; kt < 2; ++kt)
      w2f[nt][kt] = *(const bf16x8*)(w2t + (size_t)(32 * wv + nt * 16 + lr) * 64 + kt * 32 + lg * 8);
  bf16x8 w3f[4][4];
#pragma unroll
  for (int nt = 0; nt < 4; ++nt)
#pragma unroll
    for (int kt = 0; kt < 4; ++kt)
      w3f[nt][kt] = *(const bf16x8*)(w3t + (size_t)(64 * wv + nt * 16 + lr) * 128 + kt * 32 + lg * 8);

  float mxv[4];
#pragma unroll
  for (int nt = 0; nt < 4; ++nt) mxv[nt] = -INFINITY;

  for (int t0 = 0; t0 < P; t0 += 64) {
    // ---- phase A: L1 f32, wave's 16 points, lane = channel ----
#pragma unroll
    for (int pp = 0; pp < 16; ++pp) {
      const int pl = wv * 16 + pp;
      float acc = b1v;
#pragma unroll
      for (int c = 0; c < CIN; ++c) acc = fmaf(inb[c * P + t0 + pl], w1c[c], acc);
      acc = fmaxf(acc, 0.f);
      const unsigned short hi = f2bf(acc);
      const unsigned short lo = f2bf(acc - bf2f(hi));
      h1h[pl][l] = hi; h1l[pl][l] = lo;
    }
    __syncthreads();
    // ---- phase B: L2 MFMA, wave ch [32wv, 32wv+32) ----
#pragma unroll
    for (int mt = 0; mt < 4; ++mt) {
      bf16x8 ah[2], al[2];
#pragma unroll
      for (int kt = 0; kt < 2; ++kt) {
        ah[kt] = *(const bf16x8*)&h1h[mt * 16 + lr][kt * 32 + lg * 8];
        al[kt] = *(const bf16x8*)&h1l[mt * 16 + lr][kt * 32 + lg * 8];
      }
#pragma unroll
      for (int nt = 0; nt < 2; ++nt) {
        f32x4 acc = {0.f, 0.f, 0.f, 0.f};
#pragma unroll
        for (int kt = 0; kt < 2; ++kt) {
          acc = __builtin_amdgcn_mfma_f32_16x16x32_bf16(ah[kt], w2f[nt][kt], acc, 0, 0, 0);
          acc = __builtin_amdgcn_mfma_f32_16x16x32_bf16(al[kt], w2f[nt][kt], acc, 0, 0, 0);
        }
        const int ch = 32 * wv + nt * 16 + lr;
        const float b2v = b2[ch];
#pragma unroll
        for (int j = 0; j < 4; ++j) {
          const float v = fmaxf(acc[j] + b2v, 0.f);
          const unsigned short hi = f2bf(v);
          const unsigned short lo = f2bf(v - bf2f(hi));
          const int m = mt * 16 + lg * 4 + j;
          h2h[m][ch] = hi; h2l[m][ch] = lo;
        }
      }
    }
    __syncthreads();
    // ---- phase C: L3 MFMA + running max, wave ch [64wv, 64wv+64) ----
    // (no trailing barrier needed: next A writes h1 only, guarded by bar after A)
#pragma unroll
    for (int mt = 0; mt < 4; ++mt) {
      bf16x8 ah[4], al[4];
#pragma unroll
      for (int kt = 0; kt < 4; ++kt) {
        ah[kt] = *(const bf16x8*)&h2h[mt * 16 + lr][kt * 32 + lg * 8];
        al[kt] = *(const bf16x8*)&h2l[mt * 16 + lr][kt * 32 + lg * 8];
      }
#pragma unroll
      for (int nt = 0; nt < 4; ++nt) {
        f32x4 acc = {0.f, 0.f, 0.f, 0.f};
#pragma unroll
        for (int kt = 0; kt < 4; ++kt) {
          acc = __builtin_amdgcn_mfma_f32_16x16x32_bf16(ah[kt], w3f[nt][kt], acc, 0, 0, 0);
          acc = __builtin_amdgcn_mfma_f32_16x16x32_bf16(al[kt], w3f[nt][kt], acc, 0, 0, 0);
        }
        const float m4 = fmaxf(fmaxf(acc[0], acc[1]), fmaxf(acc[2], acc[3]));
        mxv[nt] = fmaxf(mxv[nt], m4);
      }
    }
  }
  // cross lane-group max (over the 4 row-groups) + store
#pragma unroll
  for (int nt = 0; nt < 4; ++nt) {
    float v = mxv[nt];
    v = fmaxf(v, __shfl_xor(v, 16));
    v = fmaxf(v, __shfl_xor(v, 32));
    if (l < 16) {
      const int ch = 64 * wv + nt * 16 + l;
      out[(size_t)b * 256 + ch] = v + b3[ch];
    }
  }
}

// ---------------- Generic tiled GEMM: C = act(A(MxK,lda) @ W(KxN) + bias) ----
template<int ACT>
__global__ __launch_bounds__(256) void gemm_kernel(
    const float* __restrict__ A, int lda,
    const float* __restrict__ W,
    const float* __restrict__ bias,
    float* __restrict__ C, int ldc,
    int M, int N, int K)
{
  __shared__ float As[16][68];
  __shared__ float Ws[16][68];
  const int tid = threadIdx.x;
  const int tx = tid & 15, ty = tid >> 4;
  const int bm = blockIdx.y * 64, bn = blockIdx.x * 64;
  float acc[4][4] = {};
  const int ar = tid >> 2, ac = (tid & 3) * 4;
  const int wr = tid >> 4, wc = (tid & 15) * 4;

  for (int k0 = 0; k0 < K; k0 += 16) {
    float4 av = make_float4(0.f, 0.f, 0.f, 0.f);
    if (bm + ar < M)
      av = *reinterpret_cast<const float4*>(&A[(size_t)(bm + ar) * lda + k0 + ac]);
    As[ac + 0][ar] = av.x; As[ac + 1][ar] = av.y;
    As[ac + 2][ar] = av.z; As[ac + 3][ar] = av.w;
#pragma unroll
    for (int i = 0; i < 4; ++i) {
      const int col = bn + wc + i;
      Ws[wr][wc + i] = (col < N) ? W[(size_t)(k0 + wr) * N + col] : 0.0f;
    }
    __syncthreads();
#pragma unroll
    for (int k = 0; k < 16; ++k) {
      const float4 a = *reinterpret_cast<const float4*>(&As[k][ty * 4]);
      const float4 bq = *reinterpret_cast<const float4*>(&Ws[k][tx * 4]);
      const float avv[4] = {a.x, a.y, a.z, a.w};
      const float bvv[4] = {bq.x, bq.y, bq.z, bq.w};
#pragma unroll
      for (int i = 0; i < 4; ++i)
#pragma unroll
        for (int j = 0; j < 4; ++j) acc[i][j] += avv[i] * bvv[j];
    }
    __syncthreads();
  }
#pragma unroll
  for (int i = 0; i < 4; ++i) {
    const int row = bm + ty * 4 + i;
    if (row >= M) continue;
#pragma unroll
    for (int j = 0; j < 4; ++j) {
      const int col = bn + tx * 4 + j;
      if (col >= N) continue;
      float v = acc[i][j] + bias[col];
      if (ACT == 1) v = fmaxf(v, 0.0f);
      else if (ACT == 2) v = 1.0f / (1.0f + expf(-v));
      C[(size_t)row * ldc + col] = v;
    }
  }
}

// ---------------- small helper kernels ----------------
__global__ __launch_bounds__(256) void gather_kernel(
    const float* __restrict__ x, const float* __restrict__ e, int estride,
    const int* __restrict__ ei, float* __restrict__ t)
{
  const int i = blockIdx.x;
  const int tid = threadIdx.x;
  const int s = ei[i], o = ei[N_EDGES + i];
  float* tr = t + (size_t)i * D3;
  tr[tid]       = x[(size_t)s * D_NODE + tid];
  tr[256 + tid] = e[(size_t)i * estride + tid];
  tr[512 + tid] = x[(size_t)o * D_NODE + tid];
}

__global__ __launch_bounds__(256) void scatter_kernel(
    const float* __restrict__ h, const int* __restrict__ ei, float* __restrict__ pooled)
{
  const int i = blockIdx.x;
  const int tid = threadIdx.x;
  const int s = ei[i], o = ei[N_EDGES + i];
  atomicAdd(&pooled[(size_t)s * D_NODE + tid], h[(size_t)i * D3 + tid]);
  atomicAdd(&pooled[(size_t)o * D_NODE + tid], h[(size_t)i * D3 + 512 + tid]);
}

__global__ __launch_bounds__(256) void count_kernel(const int* __restrict__ ei,
                                                    float* __restrict__ cnt)
{
  const int i = blockIdx.x * blockDim.x + threadIdx.x;
  if (i < 2 * N_EDGES) atomicAdd(&cnt[ei[i]], 1.0f);
}

__global__ __launch_bounds__(256) void avg_kernel(const float* __restrict__ pooled,
                                                  const float* __restrict__ cnt,
                                                  float* __restrict__ avg)
{
  const int i = blockIdx.x * 256 + threadIdx.x;
  avg[i] = pooled[i] / fmaxf(cnt[i >> 8], 1.0f);
}

__global__ __launch_bounds__(256) void logsoftmax_kernel(const float* __restrict__ logits,
                                                         float* __restrict__ out)
{
  __shared__ float red[256];
  const int r = blockIdx.x, tid = threadIdx.x;
  const float v = (tid < N_OBJ_CLS) ? logits[(size_t)r * N_OBJ_CLS + tid] : -INFINITY;
  red[tid] = v;
  __syncthreads();
  for (int s = 128; s > 0; s >>= 1) {
    if (tid < s) red[tid] = fmaxf(red[tid], red[tid + s]);
    __syncthreads();
  }
  const float mxv = red[0];
  __syncthreads();
  red[tid] = (tid < N_OBJ_CLS) ? expf(v - mxv) : 0.0f;
  __syncthreads();
  for (int s = 128; s > 0; s >>= 1) {
    if (tid < s) red[tid] += red[tid + s];
    __syncthreads();
  }
  const float lse = mxv + logf(red[0]);
  if (tid < N_OBJ_CLS) out[(size_t)r * N_OBJ_CLS + tid] = v - lse;
}

// ---------------- launch ----------------
extern "C" void kernel_launch(void* const* d_in, const int* in_sizes, int n_in,
                              void* d_out, int out_size, void* d_ws, size_t ws_size,
                              hipStream_t stream)
{
  const float* obj_points = (const float*)d_in[0];
  const float* rel_points = (const float*)d_in[1];
  const int*   edge_index = (const int*)d_in[2];
  const float* obj_w1 = (const float*)d_in[3];
  const float* obj_b1 = (const float*)d_in[4];
  const float* obj_w2 = (const float*)d_in[5];
  const float* obj_b2 = (const float*)d_in[6];
  const float* obj_w3 = (const float*)d_in[7];
  const float* obj_b3 = (const float*)d_in[8];
  const float* rel_w1 = (const float*)d_in[9];
  const float* rel_b1 = (const float*)d_in[10];
  const float* rel_w2 = (const float*)d_in[11];
  const float* rel_b2 = (const float*)d_in[12];
  const float* rel_w3 = (const float*)d_in[13];
  const float* rel_b3 = (const float*)d_in[14];
  const float* g_tw1 = (const float*)d_in[15];
  const float* g_tb1 = (const float*)d_in[16];
  const float* g_tw2 = (const float*)d_in[17];
  const float* g_tb2 = (const float*)d_in[18];
  const float* g_nw1 = (const float*)d_in[19];
  const float* g_nb1 = (const float*)d_in[20];
  const float* g_nw2 = (const float*)d_in[21];
  const float* g_nb2 = (const float*)d_in[22];
  const float* oc_w1 = (const float*)d_in[23];
  const float* oc_b1 = (const float*)d_in[24];
  const float* oc_w2 = (const float*)d_in[25];
  const float* oc_b2 = (const float*)d_in[26];
  const float* oc_w3 = (const float*)d_in[27];
  const float* oc_b3 = (const float*)d_in[28];
  const float* rc_w1 = (const float*)d_in[29];
  const float* rc_b1 = (const float*)d_in[30];
  const float* rc_w2 = (const float*)d_in[31];
  const float* rc_b2 = (const float*)d_in[32];
  const float* rc_w3 = (const float*)d_in[33];
  const float* rc_b3 = (const float*)d_in[34];
  float* out = (float*)d_out;

  float* ws = (float*)d_ws;
  size_t off = 0;
  float* x0     = ws + off; off += (size_t)N_NODES * D_NODE;
  float* x1     = ws + off; off += (size_t)N_NODES * D_NODE;
  float* e0     = ws + off; off += (size_t)N_EDGES * D_NODE;
  float* tbuf   = ws + off; off += (size_t)N_EDGES * D3;
  float* h1g    = ws + off; off += (size_t)N_EDGES * H_GNN;
  float* h2g    = ws + off; off += (size_t)N_EDGES * D3;
  float* pooled = ws + off; off += (size_t)N_NODES * D_NODE;
  float* cntf   = ws + off; off += 512;
  float* avgb   = ws + off; off += (size_t)N_NODES * D_NODE;
  float* nh     = ws + off; off += (size_t)N_NODES * H_GNN;
  // heads alias onto buffers that are dead after the GNN
  float* hh1    = tbuf;   // up to 4096x512
  float* hh2    = h1g;    // up to 4096x256
  float* logits = pooled; // 512x160

  // bf16 transposed pointnet weights live in nh (dead until the GNN node-MLP,
  // which runs long after both pointnets complete). 81,920 shorts << nh size.
  unsigned short* wsh  = (unsigned short*)nh;
  unsigned short* ow2t = wsh;               // 128x64
  unsigned short* ow3t = ow2t + 8192;       // 256x128
  unsigned short* rw2t = ow3t + 32768;      // 128x64
  unsigned short* rw3t = rw2t + 8192;       // 256x128

  // prep: transpose+cast pointnet L2/L3 weights
  wtrans_kernel<<<(64 * 128 + 255) / 256, 256, 0, stream>>>(obj_w2, ow2t, 64, 128);
  wtrans_kernel<<<(128 * 256 + 255) / 256, 256, 0, stream>>>(obj_w3, ow3t, 128, 256);
  wtrans_kernel<<<(64 * 128 + 255) / 256, 256, 0, stream>>>(rel_w2, rw2t, 64, 128);
  wtrans_kernel<<<(128 * 256 + 255) / 256, 256, 0, stream>>>(rel_w3, rw3t, 128, 256);

  // PointNets (MFMA)
  pointnet_mfma<3, 512><<<N_NODES, 256, 0, stream>>>(
      obj_points, obj_w1, obj_b1, ow2t, obj_b2, ow3t, obj_b3, x0);
  pointnet_mfma<4, 256><<<N_EDGES, 256, 0, stream>>>(
      rel_points, rel_w1, rel_b1, rw2t, rel_b2, rw3t, rel_b3, e0);

  // degree counts (same for both layers)
  hipMemsetAsync(cntf, 0, 512 * sizeof(float), stream);
  count_kernel<<<32, 256, 0, stream>>>(edge_index, cntf);

  float* xcur = x0;
  float* xnext = x1;
  const float* e_ptr = e0; int estride = D_NODE;
  for (int l = 0; l < 2; ++l) {
    gather_kernel<<<N_EDGES, 256, 0, stream>>>(xcur, e_ptr, estride, edge_index, tbuf);
    gemm_kernel<1><<<dim3(H_GNN / 64, N_EDGES / 64), 256, 0, stream>>>(
        tbuf, D3, g_tw1 + (size_t)l * D3 * H_GNN, g_tb1 + l * H_GNN,
        h1g, H_GNN, N_EDGES, H_GNN, D3);
    gemm_kernel<0><<<dim3(D3 / 64, N_EDGES / 64), 256, 0, stream>>>(
        h1g, H_GNN, g_tw2 + (size_t)l * H_GNN * D3, g_tb2 + l * D3,
        h2g, D3, N_EDGES, D3, H_GNN);
    hipMemsetAsync(pooled, 0, (size_t)N_NODES * D_NODE * sizeof(float), stream);
    scatter_kernel<<<N_EDGES, 256, 0, stream>>>(h2g, edge_index, pooled);
    avg_kernel<<<N_NODES, 256, 0, stream>>>(pooled, cntf, avgb);
    gemm_kernel<1><<<dim3(H_GNN / 64, N_NODES / 64), 256, 0, stream>>>(
        avgb, D_NODE, g_nw1 + (size_t)l * D_NODE * H_GNN, g_nb1 + l * H_GNN,
        nh, H_GNN, N_NODES, H_GNN, D_NODE);
    gemm_kernel<0><<<dim3(D_NODE / 64, N_NODES / 64), 256, 0, stream>>>(
        nh, H_GNN, g_nw2 + (size_t)l * H_GNN * D_NODE, g_nb2 + l * D_NODE,
        xnext, D_NODE, N_NODES, D_NODE, H_GNN);
    e_ptr = h2g + D_NODE; estride = D3;
    float* tmp = xcur; xcur = xnext; xnext = tmp;
  }

  // obj head: 256->512->256->160, log_softmax
  gemm_kernel<1><<<dim3(512 / 64, N_NODES / 64), 256, 0, stream>>>(
      xcur, D_NODE, oc_w1, oc_b1, hh1, 512, N_NODES, 512, 256);
  gemm_kernel<1><<<dim3(256 / 64, N_NODES / 64), 256, 0, stream>>>(
      hh1, 512, oc_w2, oc_b2, hh2, 256, N_NODES, 256, 512);
  gemm_kernel<0><<<dim3((N_OBJ_CLS + 63) / 64, N_NODES / 64), 256, 0, stream>>>(
      hh2, 256, oc_w3, oc_b3, logits, N_OBJ_CLS, N_NODES, N_OBJ_CLS, 256);
  logsoftmax_kernel<<<N_NODES, 256, 0, stream>>>(logits, out);

  // rel head: 256->512->256->26, sigmoid (e read in-place from h2g)
  gemm_kernel<1><<<dim3(512 / 64, N_EDGES / 64), 256, 0, stream>>>(
      h2g + D_NODE, D3, rc_w1, rc_b1, hh1, 512, N_EDGES, 512, 256);
  gemm_kernel<1><<<dim3(256 / 64, N_EDGES / 64), 256, 0, stream>>>(
      hh1, 512, rc_w2, rc_b2, hh2, 256, N_EDGES, 256, 512);
  gemm_kernel<2><<<dim3((N_REL_CLS + 63) / 64, N_EDGES / 64), 256, 0, stream>>>(
      hh2, 256, rc_w3, rc_b3, out + (size_t)N_NODES * N_OBJ_CLS, N_REL_CLS,
      N_EDGES, N_REL_CLS, 26 == N_REL_CLS ? 256 : 256);
}

// Round 5
// 478.623 us; speedup vs baseline: 4.9527x; 1.8498x over previous
//
#include <hip/hip_runtime.h>
#include <hip/hip_bf16.h>
#include <math.h>

#define N_NODES 512
#define N_EDGES 4096
#define D_NODE 256
#define D3 768
#define H_GNN 512
#define N_OBJ_CLS 160
#define N_REL_CLS 26

typedef __attribute__((ext_vector_type(8))) short bf16x8;   // 8 bf16 in 4 VGPRs
typedef __attribute__((ext_vector_type(4))) float f32x4;    // MFMA accumulator

__device__ __forceinline__ unsigned short f2bf(float x) {   // RNE f32 -> bf16 bits
  unsigned u = __float_as_uint(x);
  u = u + 0x7FFFu + ((u >> 16) & 1u);
  return (unsigned short)(u >> 16);
}
__device__ __forceinline__ float bf2f(unsigned short h) {
  return __uint_as_float(((unsigned)h) << 16);
}

// ---------------- batched weight transpose+split: wt[n*K+k] = hi/lo(w[k*N+n]) ----
struct WEnt { const float* src; unsigned short* dh; unsigned short* dl; int K; int N; int start; };
struct WBatch { WEnt e[18]; int total; };

__global__ __launch_bounds__(256) void wtrans_batch(WBatch wb) {
  int idx = blockIdx.x * 256 + threadIdx.x;
  const int stride = gridDim.x * 256;
  for (; idx < wb.total; idx += stride) {
    int i = 0;
#pragma unroll
    for (int t = 1; t < 18; ++t) if (idx >= wb.e[t].start) i = t;
    const int local = idx - wb.e[i].start;
    const int K = wb.e[i].K;
    const int n = local / K, k = local - n * K;
    const float v = wb.e[i].src[k * wb.e[i].N + n];
    const unsigned short hi = f2bf(v);
    wb.e[i].dh[local] = hi;
    wb.e[i].dl[local] = f2bf(v - bf2f(hi));
  }
}

// ---------------- MFMA PointNet: (B,CIN,P) -> hi/lo planes (B,256) ----------------
template<int CIN, int P>
__global__ __launch_bounds__(256) void pointnet_mfma(
    const float* __restrict__ in,
    const float* __restrict__ w1, const float* __restrict__ b1,
    const unsigned short* __restrict__ w2t, const float* __restrict__ b2,
    const unsigned short* __restrict__ w3t, const float* __restrict__ b3,
    unsigned short* __restrict__ outh, unsigned short* __restrict__ outl)
{
  __shared__ unsigned short h1h[64][72], h1l[64][72];
  __shared__ unsigned short h2h[64][136], h2l[64][136];
  const int tid = threadIdx.x;
  const int wv = tid >> 6;
  const int l  = tid & 63;
  const int lr = l & 15;
  const int lg = l >> 4;
  const int b = blockIdx.x;
  const float* inb = in + (size_t)b * CIN * P;

  float w1c[CIN];
#pragma unroll
  for (int c = 0; c < CIN; ++c) w1c[c] = w1[c * 64 + l];
  const float b1v = b1[l];

  bf16x8 w2f[2][2];
#pragma unroll
  for (int nt = 0; nt < 2; ++nt)
#pragma unroll
    for (int kt = 0; kt < 2; ++kt)
      w2f[nt][kt] = *(const bf16x8*)(w2t + (size_t)(32 * wv + nt * 16 + lr) * 64 + kt * 32 + lg * 8);
  bf16x8 w3f[4][4];
#pragma unroll
  for (int nt = 0; nt < 4; ++nt)
#pragma unroll
    for (int kt = 0; kt < 4; ++kt)
      w3f[nt][kt] = *(const bf16x8*)(w3t + (size_t)(64 * wv + nt * 16 + lr) * 128 + kt * 32 + lg * 8);

  float mxv[4];
#pragma unroll
  for (int nt = 0; nt < 4; ++nt) mxv[nt] = -INFINITY;

  for (int t0 = 0; t0 < P; t0 += 64) {
#pragma unroll
    for (int pp = 0; pp < 16; ++pp) {
      const int pl = wv * 16 + pp;
      float acc = b1v;
#pragma unroll
      for (int c = 0; c < CIN; ++c) acc = fmaf(inb[c * P + t0 + pl], w1c[c], acc);
      acc = fmaxf(acc, 0.f);
      const unsigned short hi = f2bf(acc);
      const unsigned short lo = f2bf(acc - bf2f(hi));
      h1h[pl][l] = hi; h1l[pl][l] = lo;
    }
    __syncthreads();
#pragma unroll
    for (int mt = 0; mt < 4; ++mt) {
      bf16x8 ah[2], al[2];
#pragma unroll
      for (int kt = 0; kt < 2; ++kt) {
        ah[kt] = *(const bf16x8*)&h1h[mt * 16 + lr][kt * 32 + lg * 8];
        al[kt] = *(const bf16x8*)&h1l[mt * 16 + lr][kt * 32 + lg * 8];
      }
#pragma unroll
      for (int nt = 0; nt < 2; ++nt) {
        f32x4 acc = {0.f, 0.f, 0.f, 0.f};
#pragma unroll
        for (int kt = 0; kt < 2; ++kt) {
          acc = __builtin_amdgcn_mfma_f32_16x16x32_bf16(ah[kt], w2f[nt][kt], acc, 0, 0, 0);
          acc = __builtin_amdgcn_mfma_f32_16x16x32_bf16(al[kt], w2f[nt][kt], acc, 0, 0, 0);
        }
        const int ch = 32 * wv + nt * 16 + lr;
        const float b2v = b2[ch];
#pragma unroll
        for (int j = 0; j < 4; ++j) {
          const float v = fmaxf(acc[j] + b2v, 0.f);
          const unsigned short hi = f2bf(v);
          const unsigned short lo = f2bf(v - bf2f(hi));
          const int m = mt * 16 + lg * 4 + j;
          h2h[m][ch] = hi; h2l[m][ch] = lo;
        }
      }
    }
    __syncthreads();
#pragma unroll
    for (int mt = 0; mt < 4; ++mt) {
      bf16x8 ah[4], al[4];
#pragma unroll
      for (int kt = 0; kt < 4; ++kt) {
        ah[kt] = *(const bf16x8*)&h2h[mt * 16 + lr][kt * 32 + lg * 8];
        al[kt] = *(const bf16x8*)&h2l[mt * 16 + lr][kt * 32 + lg * 8];
      }
#pragma unroll
      for (int nt = 0; nt < 4; ++nt) {
        f32x4 acc = {0.f, 0.f, 0.f, 0.f};
#pragma unroll
        for (int kt = 0; kt < 4; ++kt) {
          acc = __builtin_amdgcn_mfma_f32_16x16x32_bf16(ah[kt], w3f[nt][kt], acc, 0, 0, 0);
          acc = __builtin_amdgcn_mfma_f32_16x16x32_bf16(al[kt], w3f[nt][kt], acc, 0, 0, 0);
        }
        const float m4 = fmaxf(fmaxf(acc[0], acc[1]), fmaxf(acc[2], acc[3]));
        mxv[nt] = fmaxf(mxv[nt], m4);
      }
    }
  }
#pragma unroll
  for (int nt = 0; nt < 4; ++nt) {
    float v = mxv[nt];
    v = fmaxf(v, __shfl_xor(v, 16));
    v = fmaxf(v, __shfl_xor(v, 32));
    if (l < 16) {
      const int ch = 64 * wv + nt * 16 + l;
      const float r = v + b3[ch];
      const unsigned short hi = f2bf(r);
      outh[(size_t)b * 256 + ch] = hi;
      outl[(size_t)b * 256 + ch] = f2bf(r - bf2f(hi));
    }
  }
}

// ---------------- generic MFMA GEMM on hi/lo bf16 planes ----------------
// C(MxN) = act(A(MxK) @ W(KxN) + bias), A = Ah+Al planes, W pre-transposed [N][K] hi/lo.
// 3-term MFMA: AhWh + AlWh + AhWl (error ~2^-18).
// ACT: 0 none, 1 relu, 2 sigmoid.
// OUT: 0 = hi/lo planes; 1 = f32; 2 = GNN scatter (cols<256 atomicAdd pooled[s],
//      cols 256..511 -> ne hi/lo planes, cols>=512 atomicAdd pooled[o]).
// GATHER: A rows are edges: [x[s] | e | x[o]] with x=(Ah,Al), e=(Eh,El), stride 256.
template<int ACT, int OUT, bool GATHER>
__global__ __launch_bounds__(256) void mgemm(
    const unsigned short* __restrict__ Ah, const unsigned short* __restrict__ Al, int lda,
    const unsigned short* __restrict__ Eh, const unsigned short* __restrict__ El,
    const int* __restrict__ ei,
    const unsigned short* __restrict__ Wh, const unsigned short* __restrict__ Wl,
    const float* __restrict__ bias,
    unsigned short* __restrict__ Oh, unsigned short* __restrict__ Ol, int ldo,
    float* __restrict__ Of, float* __restrict__ pooled,
    int M, int N, int K)
{
  __shared__ unsigned short sAh[64][40], sAl[64][40];   // pad 32->40: 2-way only
  __shared__ unsigned short sBh[64][40], sBl[64][40];
  __shared__ int sS[64], sO[64];
  const int tid = threadIdx.x;
  const int wv = tid >> 6, l = tid & 63, lr = l & 15, lg = l >> 4;
  const int wm = wv >> 1, wn = wv & 1;
  const int bm = blockIdx.y * 64, bn = blockIdx.x * 64;
  const int srow = tid >> 2, sch = (tid & 3) * 8;

  if ((GATHER || OUT == 2) && tid < 64) {
    sS[tid] = ei[bm + tid];
    sO[tid] = ei[N_EDGES + bm + tid];
  }

  float bv[2];
#pragma unroll
  for (int ni = 0; ni < 2; ++ni) {
    const int col = bn + wn * 32 + ni * 16 + lr;
    bv[ni] = (col < N) ? bias[col] : 0.f;
  }

  f32x4 acc[2][2];
#pragma unroll
  for (int mi = 0; mi < 2; ++mi)
#pragma unroll
    for (int ni = 0; ni < 2; ++ni) {
      f32x4 z = {0.f, 0.f, 0.f, 0.f};
      acc[mi][ni] = z;
    }

  for (int k0 = 0; k0 < K; k0 += 32) {
    __syncthreads();   // LDS free (also covers sS/sO on first iter)
    // ---- A staging ----
    {
      const unsigned short *ph, *pl;
      if (GATHER) {
        const int kg = k0 + sch;
        if (kg < 256)      { const size_t o = (size_t)sS[srow] * 256 + kg;              ph = Ah + o; pl = Al + o; }
        else if (kg < 512) { const size_t o = (size_t)(bm + srow) * 256 + (kg - 256);   ph = Eh + o; pl = El + o; }
        else               { const size_t o = (size_t)sO[srow] * 256 + (kg - 512);      ph = Ah + o; pl = Al + o; }
      } else {
        const size_t o = (size_t)(bm + srow) * lda + k0 + sch;
        ph = Ah + o; pl = Al + o;
      }
      *(bf16x8*)&sAh[srow][sch] = *(const bf16x8*)ph;
      *(bf16x8*)&sAl[srow][sch] = *(const bf16x8*)pl;
    }
    // ---- B staging (Wt is [N][K]) ----
    {
      const int n = bn + srow;
      bf16x8 vh = {0,0,0,0,0,0,0,0}, vl = {0,0,0,0,0,0,0,0};
      if (n < N) {
        const size_t o = (size_t)n * K + k0 + sch;
        vh = *(const bf16x8*)(Wh + o);
        vl = *(const bf16x8*)(Wl + o);
      }
      *(bf16x8*)&sBh[srow][sch] = vh;
      *(bf16x8*)&sBl[srow][sch] = vl;
    }
    __syncthreads();
    // ---- fragments + MFMA ----
    bf16x8 afh[2], afl[2], bfh[2], bfl[2];
#pragma unroll
    for (int mi = 0; mi < 2; ++mi) {
      afh[mi] = *(const bf16x8*)&sAh[wm * 32 + mi * 16 + lr][lg * 8];
      afl[mi] = *(const bf16x8*)&sAl[wm * 32 + mi * 16 + lr][lg * 8];
    }
#pragma unroll
    for (int ni = 0; ni < 2; ++ni) {
      bfh[ni] = *(const bf16x8*)&sBh[wn * 32 + ni * 16 + lr][lg * 8];
      bfl[ni] = *(const bf16x8*)&sBl[wn * 32 + ni * 16 + lr][lg * 8];
    }
#pragma unroll
    for (int mi = 0; mi < 2; ++mi)
#pragma unroll
      for (int ni = 0; ni < 2; ++ni) {
        acc[mi][ni] = __builtin_amdgcn_mfma_f32_16x16x32_bf16(afh[mi], bfh[ni], acc[mi][ni], 0, 0, 0);
        acc[mi][ni] = __builtin_amdgcn_mfma_f32_16x16x32_bf16(afl[mi], bfh[ni], acc[mi][ni], 0, 0, 0);
        acc[mi][ni] = __builtin_amdgcn_mfma_f32_16x16x32_bf16(afh[mi], bfl[ni], acc[mi][ni], 0, 0, 0);
      }
  }
  // ---- epilogue ----
#pragma unroll
  for (int mi = 0; mi < 2; ++mi)
#pragma unroll
    for (int ni = 0; ni < 2; ++ni) {
      const int colb = bn + wn * 32 + ni * 16 + lr;
#pragma unroll
      for (int j = 0; j < 4; ++j) {
        const int lrow = wm * 32 + mi * 16 + lg * 4 + j;
        float v = acc[mi][ni][j] + bv[ni];
        if (ACT == 1) v = fmaxf(v, 0.f);
        else if (ACT == 2) v = 1.f / (1.f + expf(-v));
        if (OUT == 0) {
          if (colb < N) {
            const unsigned short hi = f2bf(v);
            const size_t o = (size_t)(bm + lrow) * ldo + colb;
            Oh[o] = hi; Ol[o] = f2bf(v - bf2f(hi));
          }
        } else if (OUT == 1) {
          if (colb < N) Of[(size_t)(bm + lrow) * ldo + colb] = v;
        } else {
          if (colb < 256) {
            atomicAdd(&pooled[(size_t)sS[lrow] * 256 + colb], v);
          } else if (colb < 512) {
            const unsigned short hi = f2bf(v);
            const size_t o = (size_t)(bm + lrow) * 256 + (colb - 256);
            Oh[o] = hi; Ol[o] = f2bf(v - bf2f(hi));
          } else {
            atomicAdd(&pooled[(size_t)sO[lrow] * 256 + (colb - 512)], v);
          }
        }
      }
    }
}

// ---------------- helpers ----------------
__global__ __launch_bounds__(256) void count_kernel(const int* __restrict__ ei,
                                                    float* __restrict__ cnt)
{
  const int i = blockIdx.x * blockDim.x + threadIdx.x;
  if (i < 2 * N_EDGES) atomicAdd(&cnt[ei[i]], 1.0f);
}

__global__ __launch_bounds__(256) void avg_plane_kernel(const float* __restrict__ pooled,
                                                        const float* __restrict__ cnt,
                                                        unsigned short* __restrict__ ah,
                                                        unsigned short* __restrict__ al)
{
  const int i = blockIdx.x * 256 + threadIdx.x;   // grid 512 -> 131072 elems
  const float v = pooled[i] / fmaxf(cnt[i >> 8], 1.0f);
  const unsigned short hi = f2bf(v);
  ah[i] = hi;
  al[i] = f2bf(v - bf2f(hi));
}

__global__ __launch_bounds__(256) void logsoftmax_kernel(const float* __restrict__ logits,
                                                         float* __restrict__ out)
{
  __shared__ float red[256];
  const int r = blockIdx.x, tid = threadIdx.x;
  const float v = (tid < N_OBJ_CLS) ? logits[(size_t)r * N_OBJ_CLS + tid] : -INFINITY;
  red[tid] = v;
  __syncthreads();
  for (int s = 128; s > 0; s >>= 1) {
    if (tid < s) red[tid] = fmaxf(red[tid], red[tid + s]);
    __syncthreads();
  }
  const float mxv = red[0];
  __syncthreads();
  red[tid] = (tid < N_OBJ_CLS) ? expf(v - mxv) : 0.0f;
  __syncthreads();
  for (int s = 128; s > 0; s >>= 1) {
    if (tid < s) red[tid] += red[tid + s];
    __syncthreads();
  }
  const float lse = mxv + logf(red[0]);
  if (tid < N_OBJ_CLS) out[(size_t)r * N_OBJ_CLS + tid] = v - lse;
}

// ---------------- launch ----------------
extern "C" void kernel_launch(void* const* d_in, const int* in_sizes, int n_in,
                              void* d_out, int out_size, void* d_ws, size_t ws_size,
                              hipStream_t stream)
{
  const float* obj_points = (const float*)d_in[0];
  const float* rel_points = (const float*)d_in[1];
  const int*   edge_index = (const int*)d_in[2];
  const float* obj_w1 = (const float*)d_in[3];
  const float* obj_b1 = (const float*)d_in[4];
  const float* obj_w2 = (const float*)d_in[5];
  const float* obj_b2 = (const float*)d_in[6];
  const float* obj_w3 = (const float*)d_in[7];
  const float* obj_b3 = (const float*)d_in[8];
  const float* rel_w1 = (const float*)d_in[9];
  const float* rel_b1 = (const float*)d_in[10];
  const float* rel_w2 = (const float*)d_in[11];
  const float* rel_b2 = (const float*)d_in[12];
  const float* rel_w3 = (const float*)d_in[13];
  const float* rel_b3 = (const float*)d_in[14];
  const float* g_tw1 = (const float*)d_in[15];
  const float* g_tb1 = (const float*)d_in[16];
  const float* g_tw2 = (const float*)d_in[17];
  const float* g_tb2 = (const float*)d_in[18];
  const float* g_nw1 = (const float*)d_in[19];
  const float* g_nb1 = (const float*)d_in[20];
  const float* g_nw2 = (const float*)d_in[21];
  const float* g_nb2 = (const float*)d_in[22];
  const float* oc_w1 = (const float*)d_in[23];
  const float* oc_b1 = (const float*)d_in[24];
  const float* oc_w2 = (const float*)d_in[25];
  const float* oc_b2 = (const float*)d_in[26];
  const float* oc_w3 = (const float*)d_in[27];
  const float* oc_b3 = (const float*)d_in[28];
  const float* rc_w1 = (const float*)d_in[29];
  const float* rc_b1 = (const float*)d_in[30];
  const float* rc_w2 = (const float*)d_in[31];
  const float* rc_b2 = (const float*)d_in[32];
  const float* rc_w3 = (const float*)d_in[33];
  const float* rc_b3 = (const float*)d_in[34];
  float* out = (float*)d_out;

  // ---- workspace layout (ushort region then f32 region) ----
  unsigned short* u = (unsigned short*)d_ws;
  size_t uo = 0;
  auto UA = [&](size_t n) { unsigned short* p = u + uo; uo += n; return p; };
  unsigned short* x0h = UA(131072);  unsigned short* x0l = UA(131072);
  unsigned short* x1h = UA(131072);  unsigned short* x1l = UA(131072);
  unsigned short* e0h = UA(1048576); unsigned short* e0l = UA(1048576);
  unsigned short* neh = UA(1048576); unsigned short* nel = UA(1048576);
  unsigned short* h1h = UA(2097152); unsigned short* h1l = UA(2097152);
  unsigned short* avgh = UA(131072); unsigned short* avgl = UA(131072);
  unsigned short* nhh = UA(262144);  unsigned short* nhl = UA(262144);
  // weights (hi/lo, transposed [N][K])
  unsigned short* ow2h = UA(8192);   unsigned short* ow2l = UA(8192);
  unsigned short* ow3h = UA(32768);  unsigned short* ow3l = UA(32768);
  unsigned short* rw2h = UA(8192);   unsigned short* rw2l = UA(8192);
  unsigned short* rw3h = UA(32768);  unsigned short* rw3l = UA(32768);
  unsigned short* tw1h[2], *tw1l[2], *tw2h[2], *tw2l[2], *nw1h[2], *nw1l[2], *nw2h[2], *nw2l[2];
  for (int i = 0; i < 2; ++i) { tw1h[i] = UA(393216); tw1l[i] = UA(393216); }
  for (int i = 0; i < 2; ++i) { tw2h[i] = UA(393216); tw2l[i] = UA(393216); }
  for (int i = 0; i < 2; ++i) { nw1h[i] = UA(131072); nw1l[i] = UA(131072); }
  for (int i = 0; i < 2; ++i) { nw2h[i] = UA(131072); nw2l[i] = UA(131072); }
  unsigned short* oc1h = UA(131072); unsigned short* oc1l = UA(131072);
  unsigned short* oc2h = UA(131072); unsigned short* oc2l = UA(131072);
  unsigned short* oc3h = UA(40960);  unsigned short* oc3l = UA(40960);
  unsigned short* rc1h = UA(131072); unsigned short* rc1l = UA(131072);
  unsigned short* rc2h = UA(131072); unsigned short* rc2l = UA(131072);
  unsigned short* rc3h = UA(6656);   unsigned short* rc3l = UA(6656);
  // f32 region
  float* f = (float*)(u + ((uo + 7) & ~(size_t)7));
  float* pooled = f;          // 512*256
  float* cntf   = f + 131072; // 512
  float* logits = f + 131584; // 512*160
  // head activations alias dead GNN buffers
  unsigned short* hh1h = h1h; unsigned short* hh1l = h1l;   // up to 4096x512
  unsigned short* hh2h = e0h; unsigned short* hh2l = e0l;   // up to 4096x256

  // ---- batched weight transpose/split (one launch) ----
  WBatch wb;
  int cum = 0, wi = 0;
  auto ADD = [&](const float* src, unsigned short* dh, unsigned short* dl, int K, int N) {
    wb.e[wi].src = src; wb.e[wi].dh = dh; wb.e[wi].dl = dl;
    wb.e[wi].K = K; wb.e[wi].N = N; wb.e[wi].start = cum;
    cum += K * N; ++wi;
  };
  ADD(obj_w2, ow2h, ow2l, 64, 128);
  ADD(obj_w3, ow3h, ow3l, 128, 256);
  ADD(rel_w2, rw2h, rw2l, 64, 128);
  ADD(rel_w3, rw3h, rw3l, 128, 256);
  for (int i = 0; i < 2; ++i) ADD(g_tw1 + (size_t)i * 393216, tw1h[i], tw1l[i], 768, 512);
  for (int i = 0; i < 2; ++i) ADD(g_tw2 + (size_t)i * 393216, tw2h[i], tw2l[i], 512, 768);
  for (int i = 0; i < 2; ++i) ADD(g_nw1 + (size_t)i * 131072, nw1h[i], nw1l[i], 256, 512);
  for (int i = 0; i < 2; ++i) ADD(g_nw2 + (size_t)i * 131072, nw2h[i], nw2l[i], 512, 256);
  ADD(oc_w1, oc1h, oc1l, 256, 512);
  ADD(oc_w2, oc2h, oc2l, 512, 256);
  ADD(oc_w3, oc3h, oc3l, 256, 160);
  ADD(rc_w1, rc1h, rc1l, 256, 512);
  ADD(rc_w2, rc2h, rc2l, 512, 256);
  ADD(rc_w3, rc3h, rc3l, 256, 26);
  wb.total = cum;
  wtrans_batch<<<4096, 256, 0, stream>>>(wb);

  // ---- PointNets -> hi/lo planes ----
  pointnet_mfma<3, 512><<<N_NODES, 256, 0, stream>>>(
      obj_points, obj_w1, obj_b1, ow2h, obj_b2, ow3h, obj_b3, x0h, x0l);
  pointnet_mfma<4, 256><<<N_EDGES, 256, 0, stream>>>(
      rel_points, rel_w1, rel_b1, rw2h, rel_b2, rw3h, rel_b3, e0h, e0l);

  // ---- degree counts ----
  hipMemsetAsync(cntf, 0, 512 * sizeof(float), stream);
  count_kernel<<<32, 256, 0, stream>>>(edge_index, cntf);

  // ---- GNN layers ----
  unsigned short *xch = x0h, *xcl = x0l, *xnh = x1h, *xnl = x1l;
  unsigned short *ech = e0h, *ecl = e0l;
  for (int ll = 0; ll < 2; ++ll) {
    // t-GEMM1: gathered A (4096x768) @ tw1 -> relu -> h1 planes (4096x512)
    mgemm<1, 0, true><<<dim3(8, 64), 256, 0, stream>>>(
        xch, xcl, 256, ech, ecl, edge_index, tw1h[ll], tw1l[ll], g_tb1 + ll * H_GNN,
        h1h, h1l, 512, nullptr, nullptr, N_EDGES, H_GNN, D3);
    // t-GEMM2: h1 @ tw2 -> scatter(ns,no->pooled) + ne planes
    hipMemsetAsync(pooled, 0, (size_t)N_NODES * D_NODE * sizeof(float), stream);
    mgemm<0, 2, false><<<dim3(12, 64), 256, 0, stream>>>(
        h1h, h1l, 512, nullptr, nullptr, edge_index, tw2h[ll], tw2l[ll], g_tb2 + ll * D3,
        neh, nel, 256, nullptr, pooled, N_EDGES, D3, H_GNN);
    avg_plane_kernel<<<512, 256, 0, stream>>>(pooled, cntf, avgh, avgl);
    // node MLP
    mgemm<1, 0, false><<<dim3(8, 8), 256, 0, stream>>>(
        avgh, avgl, 256, nullptr, nullptr, nullptr, nw1h[ll], nw1l[ll], g_nb1 + ll * H_GNN,
        nhh, nhl, 512, nullptr, nullptr, N_NODES, H_GNN, D_NODE);
    mgemm<0, 0, false><<<dim3(4, 8), 256, 0, stream>>>(
        nhh, nhl, 512, nullptr, nullptr, nullptr, nw2h[ll], nw2l[ll], g_nb2 + ll * D_NODE,
        xnh, xnl, 256, nullptr, nullptr, N_NODES, D_NODE, H_GNN);
    unsigned short* t;
    t = xch; xch = xnh; xnh = t;
    t = xcl; xcl = xnl; xnl = t;
    ech = neh; ecl = nel;
  }

  // ---- obj head: 256->512->256->160, log_softmax ----
  mgemm<1, 0, false><<<dim3(8, 8), 256, 0, stream>>>(
      xch, xcl, 256, nullptr, nullptr, nullptr, oc1h, oc1l, oc_b1,
      hh1h, hh1l, 512, nullptr, nullptr, N_NODES, 512, 256);
  mgemm<1, 0, false><<<dim3(4, 8), 256, 0, stream>>>(
      hh1h, hh1l, 512, nullptr, nullptr, nullptr, oc2h, oc2l, oc_b2,
      hh2h, hh2l, 256, nullptr, nullptr, N_NODES, 256, 512);
  mgemm<0, 1, false><<<dim3(3, 8), 256, 0, stream>>>(
      hh2h, hh2l, 256, nullptr, nullptr, nullptr, oc3h, oc3l, oc_b3,
      nullptr, nullptr, N_OBJ_CLS, logits, nullptr, N_NODES, N_OBJ_CLS, 256);
  logsoftmax_kernel<<<N_NODES, 256, 0, stream>>>(logits, out);

  // ---- rel head: 256->512->256->26, sigmoid ----
  mgemm<1, 0, false><<<dim3(8, 64), 256, 0, stream>>>(
      ech, ecl, 256, nullptr, nullptr, nullptr, rc1h, rc1l, rc_b1,
      hh1h, hh1l, 512, nullptr, nullptr, N_EDGES, 512, 256);
  mgemm<1, 0, false><<<dim3(4, 64), 256, 0, stream>>>(
      hh1h, hh1l, 512, nullptr, nullptr, nullptr, rc2h, rc2l, rc_b2,
      hh2h, hh2l, 256, nullptr, nullptr, N_EDGES, 256, 512);
  mgemm<2, 1, false><<<dim3(1, 64), 256, 0, stream>>>(
      hh2h, hh2l, 256, nullptr, nullptr, nullptr, rc3h, rc3l, rc_b3,
      nullptr, nullptr, N_REL_CLS, out + (size_t)N_NODES * N_OBJ_CLS, nullptr,
      N_EDGES, N_REL_CLS, 256);
}